// Round 6
// baseline (253.315 us; speedup 1.0000x reference)
//
#include <hip/hip_runtime.h>
#include <hip/hip_bf16.h>

#define N_NODES 100000
#define N_EDGES 1600000
#define DIM 128
#define BR 32
#define SCAN_B 1024
#define ESTG 2048   // LDS edge-stage capacity per block

typedef __attribute__((ext_vector_type(8))) short bf16x8;
typedef __attribute__((ext_vector_type(4))) float f32x4;
typedef __attribute__((ext_vector_type(2))) float f32x2;

// ---------------- workspace layout (int units) -----------------------------
#define OFF_ROWPTR 0
#define OFF_BSUMS  (N_NODES + 4)
#define OFF_CNTP   (OFF_BSUMS + 128)
#define OFF_TICKET (OFF_CNTP + N_NODES / 2)
#define OFF_COLSRC (OFF_TICKET + N_EDGES)
#define OFF_HB     (OFF_COLSRC + N_EDGES)
#define OFF_HF8    (OFF_HB + N_NODES * DIM / 2)
#define OFF_WB     (OFF_HF8 + N_NODES * DIM / 4)
// total ~33 MB

// round-to-nearest-even f32 -> bf16 bits
__device__ inline unsigned int f2bf(float f) {
    unsigned int u = __float_as_uint(f);
    return (u + 0x7FFFu + ((u >> 16) & 1u)) >> 16;
}

// ---------------------------------------------------------------------------
// Streaming prep: [0,6250) convert x->fp8; [6250,6506) pack weights.
// ---------------------------------------------------------------------------
__global__ __launch_bounds__(256) void conv_pack_kernel(
    const float* __restrict__ x, unsigned char* __restrict__ xf8,
    const float* __restrict__ W1l, const float* __restrict__ W1r,
    const float* __restrict__ W2l, const float* __restrict__ W2r,
    unsigned short* __restrict__ WB)
{
    const int b = blockIdx.x;
    const int tid = threadIdx.x;
    if (b < 6250) {
        long i = (long)(b * 256 + tid) * 8;
        float4 a = *(const float4*)(x + i);
        float4 c = *(const float4*)(x + i + 4);
        unsigned int w0 = 0, w1 = 0;
        w0 = __builtin_amdgcn_cvt_pk_fp8_f32(a.x, a.y, w0, false);
        w0 = __builtin_amdgcn_cvt_pk_fp8_f32(a.z, a.w, w0, true);
        w1 = __builtin_amdgcn_cvt_pk_fp8_f32(c.x, c.y, w1, false);
        w1 = __builtin_amdgcn_cvt_pk_fp8_f32(c.z, c.w, w1, true);
        uint2 o; o.x = w0; o.y = w1;
        *(uint2*)(xf8 + i) = o;
    } else {
        int t = (b - 6250) * 256 + tid;           // < 65536
        int layer = t >> 15;
        int rest  = t & 32767;
        int half  = rest >> 14;
        int idx   = rest & 16383;
        int k = idx >> 7;
        int n = idx & 127;
        const float* W = layer ? (half ? W2r : W2l) : (half ? W1r : W1l);
        int kk = half * 128 + k;
        WB[layer * 32768 + (((kk >> 3) * 128 + n) << 3) + (kk & 7)] =
            (unsigned short)f2bf(W[idx]);
    }
}

// ---------------------------------------------------------------------------
// Histogram with packed 16-bit counters (2 nodes / word) + ticket capture.
// ---------------------------------------------------------------------------
__global__ __launch_bounds__(256) void hist_kernel(
    const int* __restrict__ dst, unsigned int* __restrict__ cntp,
    int* __restrict__ ticket)
{
    int i = blockIdx.x * 256 + threadIdx.x;
    if (i >= N_EDGES / 4) return;
    int4 d = ((const int4*)dst)[i];
    int4 t;
    unsigned int r;
    r = atomicAdd(&cntp[d.x >> 1], 1u << ((d.x & 1) << 4));
    t.x = (int)((r >> ((d.x & 1) << 4)) & 0xFFFFu);
    r = atomicAdd(&cntp[d.y >> 1], 1u << ((d.y & 1) << 4));
    t.y = (int)((r >> ((d.y & 1) << 4)) & 0xFFFFu);
    r = atomicAdd(&cntp[d.z >> 1], 1u << ((d.z & 1) << 4));
    t.z = (int)((r >> ((d.z & 1) << 4)) & 0xFFFFu);
    r = atomicAdd(&cntp[d.w >> 1], 1u << ((d.w & 1) << 4));
    t.w = (int)((r >> ((d.w & 1) << 4)) & 0xFFFFu);
    ((int4*)ticket)[i] = t;
}

// ---------------------------------------------------------------------------
// Scans: exclusive prefix of (packed) degree counts -> rowptr, two-level.
// ---------------------------------------------------------------------------
__global__ __launch_bounds__(SCAN_B) void scan1_kernel(
    const unsigned int* __restrict__ cntp, int* __restrict__ rowptr,
    int* __restrict__ bsums, int n)
{
    __shared__ int tmp[SCAN_B];
    int tid = threadIdx.x;
    int gid = blockIdx.x * SCAN_B + tid;
    int v = 0;
    if (gid < n) v = (int)((cntp[gid >> 1] >> ((gid & 1) << 4)) & 0xFFFFu);
    tmp[tid] = v;
    __syncthreads();
    for (int off = 1; off < SCAN_B; off <<= 1) {
        int t = (tid >= off) ? tmp[tid - off] : 0;
        __syncthreads();
        tmp[tid] += t;
        __syncthreads();
    }
    if (gid < n) rowptr[gid] = tmp[tid] - v;
    if (tid == SCAN_B - 1) bsums[blockIdx.x] = tmp[tid];
}

__global__ void scan2_kernel(int* __restrict__ bsums, int nb)
{
    __shared__ int tmp[128];
    int tid = threadIdx.x;
    int v = (tid < nb) ? bsums[tid] : 0;
    tmp[tid] = v;
    __syncthreads();
    for (int off = 1; off < 128; off <<= 1) {
        int t = (tid >= off) ? tmp[tid - off] : 0;
        __syncthreads();
        tmp[tid] += t;
        __syncthreads();
    }
    if (tid < nb) bsums[tid] = tmp[tid] - v;
}

__global__ __launch_bounds__(256) void scan3_kernel(
    int* __restrict__ rowptr, const int* __restrict__ bsums, int n, int num_edges)
{
    int gid = blockIdx.x * 256 + threadIdx.x;
    if (gid < n) rowptr[gid] += bsums[gid / SCAN_B];
    if (gid == 0) rowptr[n] = num_edges;
}

// ---------------------------------------------------------------------------
// CSR fill: no atomics (ticket precomputed in hist pass).
// ---------------------------------------------------------------------------
__global__ __launch_bounds__(256) void fill_kernel(
    const int* __restrict__ src, const int* __restrict__ dst,
    const int* __restrict__ ticket, const int* __restrict__ rowptr,
    int* __restrict__ colsrc)
{
    int i = blockIdx.x * 256 + threadIdx.x;
    if (i >= N_EDGES / 4) return;
    int4 s = ((const int4*)src)[i];
    int4 d = ((const int4*)dst)[i];
    int4 t = ((const int4*)ticket)[i];
    colsrc[rowptr[d.x] + t.x] = s.x;
    colsrc[rowptr[d.y] + t.y] = s.y;
    colsrc[rowptr[d.z] + t.z] = s.z;
    colsrc[rowptr[d.w] + t.w] = s.w;
}

// ---------------------------------------------------------------------------
// Fused SAGE layer: gather-mean from FP8 table (128B rows), self from
// f32 (mode 1) or bf16 (mode 0); [agg|self] @ WB via mfma_f32_16x16x32_bf16.
// mode 1 dual-emits bf16 h AND fp8 h (layer-2 gather table).
// ---------------------------------------------------------------------------
__device__ inline void addfp8(float* acc, uint2 v) {
    f32x2 p;
    p = __builtin_amdgcn_cvt_pk_f32_fp8((int)v.x, false); acc[0] += p.x; acc[1] += p.y;
    p = __builtin_amdgcn_cvt_pk_f32_fp8((int)v.x, true);  acc[2] += p.x; acc[3] += p.y;
    p = __builtin_amdgcn_cvt_pk_f32_fp8((int)v.y, false); acc[4] += p.x; acc[5] += p.y;
    p = __builtin_amdgcn_cvt_pk_f32_fp8((int)v.y, true);  acc[6] += p.x; acc[7] += p.y;
}

__global__ __launch_bounds__(256, 5) void fused_sage_kernel(
    const unsigned char* __restrict__ f8,      // fp8 gather table [N][128]
    const float* __restrict__ selfF,           // mode 1: f32 self rows
    const unsigned short* __restrict__ selfB,  // mode 0: bf16 self rows
    const int* __restrict__ rowptr,
    const int* __restrict__ colsrc,
    const unsigned short* __restrict__ WB,     // fragment-major [256][128] bf16
    const float* __restrict__ bias,
    unsigned short* __restrict__ outb,         // mode 1: bf16 out (relu)
    unsigned char* __restrict__ outf8,         // mode 1: fp8 out (relu)
    float* __restrict__ outf,                  // mode 0: f32 out
    int mode)
{
    __shared__ unsigned short catS[BR * 256];  // 16 KB, 16B-slot XOR swizzle
    __shared__ int eS[ESTG];                   // 8 KB edge byte-offsets

    const int tid = threadIdx.x;
    const int block_row = blockIdx.x * BR;
    const int ebase = rowptr[block_row];
    const int span  = rowptr[block_row + BR] - ebase;
    const int smax  = span < ESTG ? span : ESTG;

    for (int i = tid; i < smax; i += 256)
        eS[i] = colsrc[ebase + i] << 7;        // byte offset (128 B/row fp8)
    __syncthreads();

    const int c   = tid & 15;                  // slot within row
    const int c8  = c * 8;
    const int grp = tid >> 4;                  // 16 gather groups

    #pragma unroll
    for (int it = 0; it < 2; ++it) {
        const int nl = grp * 2 + it;
        const int node = block_row + nl;
        const int s  = rowptr[node] - ebase;
        const int e_ = rowptr[node + 1] - ebase;
        const int lim = e_ < ESTG ? e_ : ESTG;

        // self row: issue early, consumed at the end
        uint4 sv;
        if (mode) {
            float4 sa = *(const float4*)(selfF + ((long)node << 7) + c8);
            float4 sb = *(const float4*)(selfF + ((long)node << 7) + c8 + 4);
            sv.x = f2bf(sa.x) | (f2bf(sa.y) << 16);
            sv.y = f2bf(sa.z) | (f2bf(sa.w) << 16);
            sv.z = f2bf(sb.x) | (f2bf(sb.y) << 16);
            sv.w = f2bf(sb.z) | (f2bf(sb.w) << 16);
        } else {
            sv = *(const uint4*)(selfB + ((long)node << 7) + c8);
        }

        float acc[8];
        #pragma unroll
        for (int q = 0; q < 8; ++q) acc[q] = 0.0f;

        int i = s;
        for (; i + 8 <= lim; i += 8) {
            const uint2 v0 = *(const uint2*)(f8 + eS[i + 0] + c8);
            const uint2 v1 = *(const uint2*)(f8 + eS[i + 1] + c8);
            const uint2 v2 = *(const uint2*)(f8 + eS[i + 2] + c8);
            const uint2 v3 = *(const uint2*)(f8 + eS[i + 3] + c8);
            const uint2 v4 = *(const uint2*)(f8 + eS[i + 4] + c8);
            const uint2 v5 = *(const uint2*)(f8 + eS[i + 5] + c8);
            const uint2 v6 = *(const uint2*)(f8 + eS[i + 6] + c8);
            const uint2 v7 = *(const uint2*)(f8 + eS[i + 7] + c8);
            addfp8(acc, v0); addfp8(acc, v1); addfp8(acc, v2); addfp8(acc, v3);
            addfp8(acc, v4); addfp8(acc, v5); addfp8(acc, v6); addfp8(acc, v7);
        }
        for (; i < lim; ++i) {
            const uint2 v = *(const uint2*)(f8 + eS[i] + c8);
            addfp8(acc, v);
        }
        for (; i < e_; ++i) {   // span > ESTG fallback
            const uint2 v = *(const uint2*)(f8 + ((long)colsrc[ebase + i] << 7) + c8);
            addfp8(acc, v);
        }

        const float inv = 1.0f / fmaxf((float)(e_ - s), 1.0f);
        uint4 pv;
        pv.x = f2bf(acc[0] * inv) | (f2bf(acc[1] * inv) << 16);
        pv.y = f2bf(acc[2] * inv) | (f2bf(acc[3] * inv) << 16);
        pv.z = f2bf(acc[4] * inv) | (f2bf(acc[5] * inv) << 16);
        pv.w = f2bf(acc[6] * inv) | (f2bf(acc[7] * inv) << 16);
        const int sw = c ^ (nl & 7);
        *(uint4*)&catS[nl * 256 + sw * 8] = pv;          // agg: slots 0..15
        *(uint4*)&catS[nl * 256 + 128 + sw * 8] = sv;    // self: slots 16..31
    }
    __syncthreads();

    // ---- MFMA GEMM: [32,256] @ [256,128] ----
    const int w    = tid >> 6;
    const int l    = tid & 63;
    const int wm   = w & 1;
    const int wn   = w >> 1;
    const int lrow = l & 15;
    const int kgrp = l >> 4;
    const int ar   = wm * 16 + lrow;

    f32x4 acc4[4];
    #pragma unroll
    for (int t = 0; t < 4; ++t) acc4[t] = (f32x4){0.f, 0.f, 0.f, 0.f};

    #pragma unroll
    for (int step = 0; step < 8; ++step) {
        const int slot = step * 4 + kgrp;
        bf16x8 a = *(const bf16x8*)&catS[ar * 256 + ((slot ^ (ar & 7)) << 3)];
        #pragma unroll
        for (int t = 0; t < 4; ++t) {
            const int n = wn * 64 + t * 16 + lrow;
            bf16x8 b = *(const bf16x8*)(WB + ((slot * 128 + n) << 3));
            acc4[t] = __builtin_amdgcn_mfma_f32_16x16x32_bf16(a, b, acc4[t], 0, 0, 0);
        }
    }

    // ---- epilogue ----
    const long orow0 = block_row + wm * 16 + kgrp * 4;   // D: row=(l>>4)*4+j
    const int  cbase = wn * 64 + lrow;                   //    col=l&15
    #pragma unroll
    for (int t = 0; t < 4; ++t) {
        const int col = cbase + t * 16;
        const float bb = bias[col];
        #pragma unroll
        for (int j = 0; j < 4; ++j) {
            float v = acc4[t][j] + bb;
            const long row = orow0 + j;
            if (mode) {
                v = fmaxf(v, 0.0f);
                outb[row * DIM + col] = (unsigned short)f2bf(v);
                outf8[row * DIM + col] =
                    (unsigned char)(__builtin_amdgcn_cvt_pk_fp8_f32(v, v, 0u, false) & 0xFFu);
            } else {
                outf[row * DIM + col] = v;
            }
        }
    }
}

// ---------------------------------------------------------------------------
extern "C" void kernel_launch(void* const* d_in, const int* in_sizes, int n_in,
                              void* d_out, int out_size, void* d_ws, size_t ws_size,
                              hipStream_t stream)
{
    const float* x   = (const float*)d_in[0];
    const int*   ei  = (const int*)d_in[1];
    const float* W1l = (const float*)d_in[2];
    const float* b1  = (const float*)d_in[3];
    const float* W1r = (const float*)d_in[4];
    const float* W2l = (const float*)d_in[5];
    const float* b2  = (const float*)d_in[6];
    const float* W2r = (const float*)d_in[7];
    float* out = (float*)d_out;

    const int* src = ei;
    const int* dst = ei + N_EDGES;

    int* wsi = (int*)d_ws;
    int* rowptr = wsi + OFF_ROWPTR;
    int* bsums  = wsi + OFF_BSUMS;
    unsigned int* cntp = (unsigned int*)(wsi + OFF_CNTP);
    int* ticket = wsi + OFF_TICKET;
    int* colsrc = wsi + OFF_COLSRC;
    unsigned short* hb  = (unsigned short*)(wsi + OFF_HB);
    unsigned char*  hf8 = (unsigned char*)(wsi + OFF_HF8);
    unsigned short* WB  = (unsigned short*)(wsi + OFF_WB);

    // xf8 lives in d_out (dead before layer-2 fused overwrites d_out with f32)
    unsigned char* xf8 = (unsigned char*)d_out;

    hipMemsetAsync(cntp, 0, (size_t)(N_NODES / 2) * sizeof(int), stream);

    conv_pack_kernel<<<6506, 256, 0, stream>>>(x, xf8, W1l, W1r, W2l, W2r, WB);
    hist_kernel<<<(N_EDGES / 4 + 255) / 256, 256, 0, stream>>>(dst, cntp, ticket);

    const int sblocks = (N_NODES + SCAN_B - 1) / SCAN_B;   // 98
    scan1_kernel<<<sblocks, SCAN_B, 0, stream>>>(cntp, rowptr, bsums, N_NODES);
    scan2_kernel<<<1, 128, 0, stream>>>(bsums, sblocks);
    scan3_kernel<<<(N_NODES + 255) / 256, 256, 0, stream>>>(
        rowptr, bsums, N_NODES, N_EDGES);

    fill_kernel<<<(N_EDGES / 4 + 255) / 256, 256, 0, stream>>>(
        src, dst, ticket, rowptr, colsrc);

    const int gblocks = N_NODES / BR;   // 3125
    // layer 1: gather fp8(x), self f32 x -> hb bf16 + hf8 fp8 (relu)
    fused_sage_kernel<<<gblocks, 256, 0, stream>>>(
        xf8, x, (const unsigned short*)nullptr, rowptr, colsrc,
        WB, b1, hb, hf8, (float*)nullptr, 1);
    // layer 2: gather fp8(h), self bf16 h -> out f32
    fused_sage_kernel<<<gblocks, 256, 0, stream>>>(
        hf8, (const float*)nullptr, hb, rowptr, colsrc,
        WB + 32768, b2, (unsigned short*)nullptr, (unsigned char*)nullptr, out, 0);
}

// Round 7
// 216.667 us; speedup vs baseline: 1.1691x; 1.1691x over previous
//
#include <hip/hip_runtime.h>
#include <hip/hip_bf16.h>

#define N_NODES 100000
#define N_EDGES 1600000
#define DIM 128
#define BR 32
#define ESTG 2048   // LDS edge-stage capacity per fused block
#define NB 782      // buckets of 128 nodes
#define CHUNK 16384 // edges per binning block

typedef __attribute__((ext_vector_type(8))) short bf16x8;
typedef __attribute__((ext_vector_type(4))) float f32x4;
typedef __attribute__((ext_vector_type(2))) float f32x2;

// ---------------- workspace layout (int units) -----------------------------
#define OFF_ROWPTR 0
#define OFF_BCNT   (N_NODES + 4)
#define OFF_BBASE  (OFF_BCNT + NB)
#define OFF_BCUR   (OFF_BBASE + NB)
#define OFF_PAIRS  (OFF_BCUR + NB)
#define OFF_COLSRC (OFF_PAIRS + N_EDGES)
#define OFF_HB     (OFF_COLSRC + N_EDGES)
#define OFF_HF8    (OFF_HB + N_NODES * DIM / 2)
#define OFF_WB     (OFF_HF8 + N_NODES * DIM / 4)
// total ~51.7 MB

// round-to-nearest-even f32 -> bf16 bits
__device__ inline unsigned int f2bf(float f) {
    unsigned int u = __float_as_uint(f);
    return (u + 0x7FFFu + ((u >> 16) & 1u)) >> 16;
}

// ---------------------------------------------------------------------------
// Streaming prep: [0,6250) convert x->fp8; [6250,6506) pack weights.
// ---------------------------------------------------------------------------
__global__ __launch_bounds__(256) void conv_pack_kernel(
    const float* __restrict__ x, unsigned char* __restrict__ xf8,
    const float* __restrict__ W1l, const float* __restrict__ W1r,
    const float* __restrict__ W2l, const float* __restrict__ W2r,
    unsigned short* __restrict__ WB)
{
    const int b = blockIdx.x;
    const int tid = threadIdx.x;
    if (b < 6250) {
        long i = (long)(b * 256 + tid) * 8;
        float4 a = *(const float4*)(x + i);
        float4 c = *(const float4*)(x + i + 4);
        unsigned int w0 = 0, w1 = 0;
        w0 = __builtin_amdgcn_cvt_pk_fp8_f32(a.x, a.y, w0, false);
        w0 = __builtin_amdgcn_cvt_pk_fp8_f32(a.z, a.w, w0, true);
        w1 = __builtin_amdgcn_cvt_pk_fp8_f32(c.x, c.y, w1, false);
        w1 = __builtin_amdgcn_cvt_pk_fp8_f32(c.z, c.w, w1, true);
        uint2 o; o.x = w0; o.y = w1;
        *(uint2*)(xf8 + i) = o;
    } else {
        int t = (b - 6250) * 256 + tid;           // < 65536
        int layer = t >> 15;
        int rest  = t & 32767;
        int half  = rest >> 14;
        int idx   = rest & 16383;
        int k = idx >> 7;
        int n = idx & 127;
        const float* W = layer ? (half ? W2r : W2l) : (half ? W1r : W1l);
        int kk = half * 128 + k;
        WB[layer * 32768 + (((kk >> 3) * 128 + n) << 3) + (kk & 7)] =
            (unsigned short)f2bf(W[idx]);
    }
}

// ---------------------------------------------------------------------------
// K1: per-block LDS histogram of dst>>7 -> global bucket counts.
// ---------------------------------------------------------------------------
__global__ __launch_bounds__(256) void bhist_kernel(
    const int* __restrict__ dst, int* __restrict__ bcnt)
{
    __shared__ int histL[NB];
    const int tid = threadIdx.x;
    const int e0 = blockIdx.x * CHUNK;
    const int e1 = min(e0 + CHUNK, N_EDGES);
    for (int b = tid; b < NB; b += 256) histL[b] = 0;
    __syncthreads();
    for (int i = e0 + tid; i < e1; i += 256)
        atomicAdd(&histL[dst[i] >> 7], 1);
    __syncthreads();
    for (int b = tid; b < NB; b += 256) {
        int c = histL[b];
        if (c) atomicAdd(&bcnt[b], c);
    }
}

// ---------------------------------------------------------------------------
// K2: exclusive scan of bucket counts -> bbase, bcur; rowptr[N]=E.
// ---------------------------------------------------------------------------
__global__ __launch_bounds__(1024) void bscan_kernel(
    const int* __restrict__ bcnt, int* __restrict__ bbase,
    int* __restrict__ bcur, int* __restrict__ rowptr)
{
    __shared__ int tmp[1024];
    int tid = threadIdx.x;
    int v = (tid < NB) ? bcnt[tid] : 0;
    tmp[tid] = v;
    __syncthreads();
    for (int off = 1; off < 1024; off <<= 1) {
        int t = (tid >= off) ? tmp[tid - off] : 0;
        __syncthreads();
        tmp[tid] += t;
        __syncthreads();
    }
    if (tid < NB) { int b = tmp[tid] - v; bbase[tid] = b; bcur[tid] = b; }
    if (tid == 0) rowptr[N_NODES] = N_EDGES;
}

// ---------------------------------------------------------------------------
// K3: bin edges into bucket regions as packed (src | dstlow<<25) pairs.
// Per-(block,bucket) contiguous sub-ranges claimed via cursor atomics.
// ---------------------------------------------------------------------------
__global__ __launch_bounds__(256) void bfill_kernel(
    const int* __restrict__ src, const int* __restrict__ dst,
    int* __restrict__ bcur, unsigned int* __restrict__ pairs)
{
    __shared__ int histL[NB];
    __shared__ int baseL[NB];
    const int tid = threadIdx.x;
    const int e0 = blockIdx.x * CHUNK;
    const int e1 = min(e0 + CHUNK, N_EDGES);
    for (int b = tid; b < NB; b += 256) histL[b] = 0;
    __syncthreads();
    for (int i = e0 + tid; i < e1; i += 256)
        atomicAdd(&histL[dst[i] >> 7], 1);
    __syncthreads();
    for (int b = tid; b < NB; b += 256) {
        int c = histL[b];
        baseL[b] = c ? atomicAdd(&bcur[b], c) : 0;
        histL[b] = 0;
    }
    __syncthreads();
    for (int i = e0 + tid; i < e1; i += 256) {
        int s = src[i];
        int d = dst[i];
        int bk = d >> 7;
        int r = atomicAdd(&histL[bk], 1);
        pairs[baseL[bk] + r] = (unsigned int)s | ((unsigned int)(d & 127) << 25);
    }
}

// ---------------------------------------------------------------------------
// K4: per-bucket exact CSR (128-node LDS hist + scan + LDS tickets).
// Writes rowptr (coalesced) and colsrc (bucket-local scatter).
// ---------------------------------------------------------------------------
__global__ __launch_bounds__(256) void bucket_csr_kernel(
    const unsigned int* __restrict__ pairs,
    const int* __restrict__ bcnt, const int* __restrict__ bbase,
    int* __restrict__ rowptr, int* __restrict__ colsrc)
{
    __shared__ int histA[128], exclS[128], hist2[128];
    const int bucket = blockIdx.x;
    const int tid = threadIdx.x;
    const int cnt  = bcnt[bucket];
    const int base = bbase[bucket];
    if (tid < 128) { histA[tid] = 0; hist2[tid] = 0; }
    __syncthreads();
    for (int i = tid; i < cnt; i += 256)
        atomicAdd(&histA[pairs[base + i] >> 25], 1);
    __syncthreads();
    int v = 0;
    if (tid < 128) { v = histA[tid]; exclS[tid] = v; }
    __syncthreads();
    for (int off = 1; off < 128; off <<= 1) {
        int t = 0;
        if (tid < 128 && tid >= off) t = exclS[tid - off];
        __syncthreads();
        if (tid < 128) exclS[tid] += t;
        __syncthreads();
    }
    if (tid < 128) exclS[tid] -= v;    // exclusive
    const int node0 = bucket * 128;
    if (tid < 128 && node0 + tid < N_NODES)
        rowptr[node0 + tid] = base + exclS[tid];
    __syncthreads();
    for (int i = tid; i < cnt; i += 256) {
        unsigned int p = pairs[base + i];
        int dl = (int)(p >> 25);
        int r = atomicAdd(&hist2[dl], 1);
        colsrc[base + exclS[dl] + r] = (int)(p & 0x1FFFFFFu);
    }
}

// ---------------------------------------------------------------------------
// Fused SAGE layer: gather-mean from FP8 table (128B rows), self from
// f32 (mode 1) or bf16 (mode 0); [agg|self] @ WB via mfma_f32_16x16x32_bf16.
// mode 1 dual-emits bf16 h AND fp8 h (layer-2 gather table).
// ---------------------------------------------------------------------------
__device__ inline void addfp8(float* acc, uint2 v) {
    f32x2 p;
    p = __builtin_amdgcn_cvt_pk_f32_fp8((int)v.x, false); acc[0] += p.x; acc[1] += p.y;
    p = __builtin_amdgcn_cvt_pk_f32_fp8((int)v.x, true);  acc[2] += p.x; acc[3] += p.y;
    p = __builtin_amdgcn_cvt_pk_f32_fp8((int)v.y, false); acc[4] += p.x; acc[5] += p.y;
    p = __builtin_amdgcn_cvt_pk_f32_fp8((int)v.y, true);  acc[6] += p.x; acc[7] += p.y;
}

__global__ __launch_bounds__(256, 5) void fused_sage_kernel(
    const unsigned char* __restrict__ f8,      // fp8 gather table [N][128]
    const float* __restrict__ selfF,           // mode 1: f32 self rows
    const unsigned short* __restrict__ selfB,  // mode 0: bf16 self rows
    const int* __restrict__ rowptr,
    const int* __restrict__ colsrc,
    const unsigned short* __restrict__ WB,     // fragment-major [256][128] bf16
    const float* __restrict__ bias,
    unsigned short* __restrict__ outb,         // mode 1: bf16 out (relu)
    unsigned char* __restrict__ outf8,         // mode 1: fp8 out (relu)
    float* __restrict__ outf,                  // mode 0: f32 out
    int mode)
{
    __shared__ unsigned short catS[BR * 256];  // 16 KB, 16B-slot XOR swizzle
    __shared__ int eS[ESTG];                   // 8 KB edge byte-offsets

    const int tid = threadIdx.x;
    const int block_row = blockIdx.x * BR;
    const int ebase = rowptr[block_row];
    const int span  = rowptr[block_row + BR] - ebase;
    const int smax  = span < ESTG ? span : ESTG;

    for (int i = tid; i < smax; i += 256)
        eS[i] = colsrc[ebase + i] << 7;        // byte offset (128 B/row fp8)
    __syncthreads();

    const int c   = tid & 15;                  // slot within row
    const int c8  = c * 8;
    const int grp = tid >> 4;                  // 16 gather groups

    #pragma unroll
    for (int it = 0; it < 2; ++it) {
        const int nl = grp * 2 + it;
        const int node = block_row + nl;
        const int s  = rowptr[node] - ebase;
        const int e_ = rowptr[node + 1] - ebase;
        const int lim = e_ < ESTG ? e_ : ESTG;

        // self row: issue early, consumed at the end
        uint4 sv;
        if (mode) {
            float4 sa = *(const float4*)(selfF + ((long)node << 7) + c8);
            float4 sb = *(const float4*)(selfF + ((long)node << 7) + c8 + 4);
            sv.x = f2bf(sa.x) | (f2bf(sa.y) << 16);
            sv.y = f2bf(sa.z) | (f2bf(sa.w) << 16);
            sv.z = f2bf(sb.x) | (f2bf(sb.y) << 16);
            sv.w = f2bf(sb.z) | (f2bf(sb.w) << 16);
        } else {
            sv = *(const uint4*)(selfB + ((long)node << 7) + c8);
        }

        float acc[8];
        #pragma unroll
        for (int q = 0; q < 8; ++q) acc[q] = 0.0f;

        int i = s;
        for (; i + 8 <= lim; i += 8) {
            const uint2 v0 = *(const uint2*)(f8 + eS[i + 0] + c8);
            const uint2 v1 = *(const uint2*)(f8 + eS[i + 1] + c8);
            const uint2 v2 = *(const uint2*)(f8 + eS[i + 2] + c8);
            const uint2 v3 = *(const uint2*)(f8 + eS[i + 3] + c8);
            const uint2 v4 = *(const uint2*)(f8 + eS[i + 4] + c8);
            const uint2 v5 = *(const uint2*)(f8 + eS[i + 5] + c8);
            const uint2 v6 = *(const uint2*)(f8 + eS[i + 6] + c8);
            const uint2 v7 = *(const uint2*)(f8 + eS[i + 7] + c8);
            addfp8(acc, v0); addfp8(acc, v1); addfp8(acc, v2); addfp8(acc, v3);
            addfp8(acc, v4); addfp8(acc, v5); addfp8(acc, v6); addfp8(acc, v7);
        }
        for (; i < lim; ++i) {
            const uint2 v = *(const uint2*)(f8 + eS[i] + c8);
            addfp8(acc, v);
        }
        for (; i < e_; ++i) {   // span > ESTG fallback
            const uint2 v = *(const uint2*)(f8 + ((long)colsrc[ebase + i] << 7) + c8);
            addfp8(acc, v);
        }

        const float inv = 1.0f / fmaxf((float)(e_ - s), 1.0f);
        uint4 pv;
        pv.x = f2bf(acc[0] * inv) | (f2bf(acc[1] * inv) << 16);
        pv.y = f2bf(acc[2] * inv) | (f2bf(acc[3] * inv) << 16);
        pv.z = f2bf(acc[4] * inv) | (f2bf(acc[5] * inv) << 16);
        pv.w = f2bf(acc[6] * inv) | (f2bf(acc[7] * inv) << 16);
        const int sw = c ^ (nl & 7);
        *(uint4*)&catS[nl * 256 + sw * 8] = pv;          // agg: slots 0..15
        *(uint4*)&catS[nl * 256 + 128 + sw * 8] = sv;    // self: slots 16..31
    }
    __syncthreads();

    // ---- MFMA GEMM: [32,256] @ [256,128] ----
    const int w    = tid >> 6;
    const int l    = tid & 63;
    const int wm   = w & 1;
    const int wn   = w >> 1;
    const int lrow = l & 15;
    const int kgrp = l >> 4;
    const int ar   = wm * 16 + lrow;

    f32x4 acc4[4];
    #pragma unroll
    for (int t = 0; t < 4; ++t) acc4[t] = (f32x4){0.f, 0.f, 0.f, 0.f};

    #pragma unroll
    for (int step = 0; step < 8; ++step) {
        const int slot = step * 4 + kgrp;
        bf16x8 a = *(const bf16x8*)&catS[ar * 256 + ((slot ^ (ar & 7)) << 3)];
        #pragma unroll
        for (int t = 0; t < 4; ++t) {
            const int n = wn * 64 + t * 16 + lrow;
            bf16x8 b = *(const bf16x8*)(WB + ((slot * 128 + n) << 3));
            acc4[t] = __builtin_amdgcn_mfma_f32_16x16x32_bf16(a, b, acc4[t], 0, 0, 0);
        }
    }

    // ---- epilogue ----
    const long orow0 = block_row + wm * 16 + kgrp * 4;   // D: row=(l>>4)*4+j
    const int  cbase = wn * 64 + lrow;                   //    col=l&15
    #pragma unroll
    for (int t = 0; t < 4; ++t) {
        const int col = cbase + t * 16;
        const float bb = bias[col];
        #pragma unroll
        for (int j = 0; j < 4; ++j) {
            float v = acc4[t][j] + bb;
            const long row = orow0 + j;
            if (mode) {
                v = fmaxf(v, 0.0f);
                outb[row * DIM + col] = (unsigned short)f2bf(v);
                outf8[row * DIM + col] =
                    (unsigned char)(__builtin_amdgcn_cvt_pk_fp8_f32(v, v, 0u, false) & 0xFFu);
            } else {
                outf[row * DIM + col] = v;
            }
        }
    }
}

// ---------------------------------------------------------------------------
extern "C" void kernel_launch(void* const* d_in, const int* in_sizes, int n_in,
                              void* d_out, int out_size, void* d_ws, size_t ws_size,
                              hipStream_t stream)
{
    const float* x   = (const float*)d_in[0];
    const int*   ei  = (const int*)d_in[1];
    const float* W1l = (const float*)d_in[2];
    const float* b1  = (const float*)d_in[3];
    const float* W1r = (const float*)d_in[4];
    const float* W2l = (const float*)d_in[5];
    const float* b2  = (const float*)d_in[6];
    const float* W2r = (const float*)d_in[7];
    float* out = (float*)d_out;

    const int* src = ei;
    const int* dst = ei + N_EDGES;

    int* wsi = (int*)d_ws;
    int* rowptr = wsi + OFF_ROWPTR;
    int* bcnt   = wsi + OFF_BCNT;
    int* bbase  = wsi + OFF_BBASE;
    int* bcur   = wsi + OFF_BCUR;
    unsigned int* pairs = (unsigned int*)(wsi + OFF_PAIRS);
    int* colsrc = wsi + OFF_COLSRC;
    unsigned short* hb  = (unsigned short*)(wsi + OFF_HB);
    unsigned char*  hf8 = (unsigned char*)(wsi + OFF_HF8);
    unsigned short* WB  = (unsigned short*)(wsi + OFF_WB);

    // xf8 lives in d_out (dead before layer-2 fused overwrites d_out with f32)
    unsigned char* xf8 = (unsigned char*)d_out;

    hipMemsetAsync(bcnt, 0, (size_t)NB * sizeof(int), stream);

    conv_pack_kernel<<<6506, 256, 0, stream>>>(x, xf8, W1l, W1r, W2l, W2r, WB);

    const int eblocks = (N_EDGES + CHUNK - 1) / CHUNK;   // 98
    bhist_kernel<<<eblocks, 256, 0, stream>>>(dst, bcnt);
    bscan_kernel<<<1, 1024, 0, stream>>>(bcnt, bbase, bcur, rowptr);
    bfill_kernel<<<eblocks, 256, 0, stream>>>(src, dst, bcur, pairs);
    bucket_csr_kernel<<<NB, 256, 0, stream>>>(pairs, bcnt, bbase, rowptr, colsrc);

    const int gblocks = N_NODES / BR;   // 3125
    // layer 1: gather fp8(x), self f32 x -> hb bf16 + hf8 fp8 (relu)
    fused_sage_kernel<<<gblocks, 256, 0, stream>>>(
        xf8, x, (const unsigned short*)nullptr, rowptr, colsrc,
        WB, b1, hb, hf8, (float*)nullptr, 1);
    // layer 2: gather fp8(h), self bf16 h -> out f32
    fused_sage_kernel<<<gblocks, 256, 0, stream>>>(
        hf8, (const float*)nullptr, hb, rowptr, colsrc,
        WB + 32768, b2, (unsigned short*)nullptr, (unsigned char*)nullptr, out, 0);
}